// Round 1
// baseline (8701.216 us; speedup 1.0000x reference)
//
#include <hip/hip_runtime.h>

// B=256, T=512, I=128, H=256, 4H=1024
// 64 persistent blocks = 4 row-groups (64 batch rows each) x 16 col-groups (16 hidden units each).
// Per step: gates tile [64 rows x 64 gate-cols], K=384 ([x|h] or [pred|h]).
// Decoder: every block redundantly computes full pred rows [64 x 128] (lin_W in LDS).

typedef __bf16 bf16;
typedef bf16 bf16x8 __attribute__((ext_vector_type(8)));
typedef float f32x4 __attribute__((ext_vector_type(4)));

#define MFMA16(a, b, c) __builtin_amdgcn_mfma_f32_16x16x32_bf16((a), (b), (c), 0, 0, 0)

__device__ __forceinline__ float sigm(float x) { return 1.0f / (1.0f + __expf(-x)); }
__device__ __forceinline__ float tanhfast(float x) { return 1.0f - 2.0f / (__expf(2.0f * x) + 1.0f); }

// ---------------- weight packing ----------------
// gate weights per col-group cg: Bg[ks=12][n=4][lane=64][e=8] bf16 (24576 elems)
//   value = Wt[k][col], k = ks*32 + (lane>>4)*8 + e, col = n*256 + cg*16 + (lane&15)
//   k<128 -> W_ih[col][k]; k>=128 -> W_hh[col][k-128]
// lin weights: Lw[ks=8][n=8][lane][e], value = lin_W[col][k], col = n*16+(lane&15), k = ks*32+(lane>>4)*8+e
__global__ void pack_kernel(const float* __restrict__ eWih, const float* __restrict__ eWhh,
                            const float* __restrict__ dWih, const float* __restrict__ dWhh,
                            const float* __restrict__ linW,
                            bf16* __restrict__ encB, bf16* __restrict__ decB, bf16* __restrict__ linB) {
    int idx = blockIdx.x * 256 + threadIdx.x;  // 0 .. 819199
    if (idx < 786432) {
        int which = idx / 393216;          // 0 = enc, 1 = dec
        int id = idx % 393216;
        int cg = id / 24576;
        int rem = id % 24576;
        int ks = rem / 2048;
        int n = (rem / 512) & 3;
        int lane = (rem >> 3) & 63;
        int e = rem & 7;
        int k = ks * 32 + (lane >> 4) * 8 + e;
        int col = n * 256 + cg * 16 + (lane & 15);
        const float* Wih = which ? dWih : eWih;
        const float* Whh = which ? dWhh : eWhh;
        float v = (k < 128) ? Wih[col * 128 + k] : Whh[col * 256 + (k - 128)];
        (which ? decB : encB)[id] = (bf16)v;
    } else if (idx < 819200) {
        int i3 = idx - 786432;             // 0 .. 32767
        int ks = i3 >> 12;
        int n = (i3 >> 9) & 7;
        int lane = (i3 >> 3) & 63;
        int e = i3 & 7;
        int k = ks * 32 + (lane >> 4) * 8 + e;
        int col = n * 16 + (lane & 15);
        linB[i3] = (bf16)linW[col * 256 + k];
    }
}

__global__ void zero_kernel(unsigned* __restrict__ p) {
    int i = blockIdx.x * 256 + threadIdx.x;
    if (i < 65792) p[i] = 0u;  // h ping-pong (65536 words) + barrier counters (256 words)
}

// ---------------- main persistent kernel ----------------
__global__ __launch_bounds__(256)
void lstm_main(const float* __restrict__ x,
               const float* __restrict__ eb_ih, const float* __restrict__ eb_hh,
               const float* __restrict__ db_ih, const float* __restrict__ db_hh,
               const float* __restrict__ lin_b,
               const bf16* __restrict__ encB, const bf16* __restrict__ decB,
               const bf16* __restrict__ linB,
               bf16* __restrict__ hbuf, unsigned* __restrict__ bars,
               float* __restrict__ out) {
    __shared__ bf16 Bg[24576];        // 48 KB gate-weight fragments (this cg)
    __shared__ bf16 Lw[32768];        // 64 KB lin_W fragments (decoder)
    __shared__ bf16 Pst[4 * 16 * 136];// 17 KB pred staging, per-wave, pitch 136 (bank-spread)

    const int bid = blockIdx.x;
    const int rg = bid >> 4;          // row-group 0..3  (64 batch rows)
    const int cg = bid & 15;          // col-group 0..15 (16 hidden units)
    const int tid = threadIdx.x;
    const int w = tid >> 6;
    const int lane = tid & 63;
    const int l15 = lane & 15, l4 = lane >> 4;
    const int rbase = rg * 64 + w * 16;       // wave's 16 batch rows
    const int ucol = cg * 16 + l15;           // this lane's hidden unit
    const int arow = rbase + l15;             // A-fragment row this lane loads
    const int k0 = l4 * 8;                    // A-fragment k sub-offset
    const int prow = rbase + l4 * 4;          // epilogue row base

    // load encoder gate weights into LDS
    {
        const f32x4* src = (const f32x4*)(encB + cg * 24576);
        f32x4* dst = (f32x4*)Bg;
        #pragma unroll
        for (int i = 0; i < 12; i++) dst[tid + 256 * i] = src[tid + 256 * i];
    }
    float bias_g[4];
    #pragma unroll
    for (int g = 0; g < 4; g++) bias_g[g] = eb_ih[g * 256 + ucol] + eb_hh[g * 256 + ucol];
    __syncthreads();

    unsigned* ctr = bars + rg * 64;   // 256B-padded per row-group
    unsigned bar_target = 0;
    float c[4] = {0.f, 0.f, 0.f, 0.f};

    // =================== encoder: 512 steps ===================
    for (int t = 0; t < 512; t++) {
        const bf16* hr = hbuf + (t & 1) * 65536;
        bf16* hw = hbuf + ((t + 1) & 1) * 65536;

        f32x4 acc[4];
        #pragma unroll
        for (int n = 0; n < 4; n++) acc[n] = (f32x4){0.f, 0.f, 0.f, 0.f};

        // x part (K 0..127): load fp32, convert to bf16
        const float* xbase = x + ((size_t)arow * 512 + t) * 128 + k0;
        #pragma unroll
        for (int ks = 0; ks < 4; ks++) {
            f32x4 xa = *(const f32x4*)(xbase + ks * 32);
            f32x4 xb = *(const f32x4*)(xbase + ks * 32 + 4);
            bf16x8 a;
            a[0] = (bf16)xa[0]; a[1] = (bf16)xa[1]; a[2] = (bf16)xa[2]; a[3] = (bf16)xa[3];
            a[4] = (bf16)xb[0]; a[5] = (bf16)xb[1]; a[6] = (bf16)xb[2]; a[7] = (bf16)xb[3];
            #pragma unroll
            for (int n = 0; n < 4; n++) {
                bf16x8 b = *(const bf16x8*)&Bg[((ks * 4 + n) * 64 + lane) * 8];
                acc[n] = MFMA16(a, b, acc[n]);
            }
        }
        // h part (K 128..383): bf16 direct from global (L2/L3-resident)
        const bf16* hbase = hr + arow * 256 + k0;
        #pragma unroll
        for (int ks = 0; ks < 8; ks++) {
            bf16x8 a = *(const bf16x8*)(hbase + ks * 32);
            #pragma unroll
            for (int n = 0; n < 4; n++) {
                bf16x8 b = *(const bf16x8*)&Bg[(((ks + 4) * 4 + n) * 64 + lane) * 8];
                acc[n] = MFMA16(a, b, acc[n]);
            }
        }
        // epilogue: lane owns rows prow+r, unit ucol; gates i,f,g,o = acc[0..3]
        #pragma unroll
        for (int r = 0; r < 4; r++) {
            float gi = sigm(acc[0][r] + bias_g[0]);
            float gf = sigm(acc[1][r] + bias_g[1]);
            float gg = tanhfast(acc[2][r] + bias_g[2]);
            float go = sigm(acc[3][r] + bias_g[3]);
            c[r] = gf * c[r] + gi * gg;
            float h = go * tanhfast(c[r]);
            hw[(prow + r) * 256 + ucol] = (bf16)h;
        }
        // row-group barrier (16 members)
        bar_target += 16;
        __syncthreads();
        if (tid == 0) {
            __threadfence();
            atomicAdd(ctr, 1u);
            while (__hip_atomic_load(ctr, __ATOMIC_RELAXED, __HIP_MEMORY_SCOPE_AGENT) < bar_target)
                __builtin_amdgcn_s_sleep(2);
            __threadfence();
        }
        __syncthreads();
    }

    // =================== switch to decoder weights ===================
    {
        const f32x4* src = (const f32x4*)(decB + cg * 24576);
        f32x4* dst = (f32x4*)Bg;
        #pragma unroll
        for (int i = 0; i < 12; i++) dst[tid + 256 * i] = src[tid + 256 * i];
        const f32x4* s2 = (const f32x4*)linB;
        f32x4* d2 = (f32x4*)Lw;
        #pragma unroll
        for (int i = 0; i < 16; i++) d2[tid + 256 * i] = s2[tid + 256 * i];
    }
    #pragma unroll
    for (int g = 0; g < 4; g++) bias_g[g] = db_ih[g * 256 + ucol] + db_hh[g * 256 + ucol];
    float lbias[8];
    #pragma unroll
    for (int n = 0; n < 8; n++) lbias[n] = lin_b[n * 16 + l15];
    __syncthreads();

    // =================== decoder: pred(k) then gates(k), k = 0..511 ===================
    for (int k = 0; k < 512; k++) {
        const bf16* hr = hbuf + (k & 1) * 65536;

        // load h A-fragments once; reused by pred GEMM and gates h-part
        bf16x8 ha[8];
        const bf16* hbase = hr + arow * 256 + k0;
        #pragma unroll
        for (int ks = 0; ks < 8; ks++) ha[ks] = *(const bf16x8*)(hbase + ks * 32);

        // pred = sigmoid(h @ lin_W^T + lin_b)  [64 x 128], redundant per block
        f32x4 pacc[8];
        #pragma unroll
        for (int n = 0; n < 8; n++) pacc[n] = (f32x4){0.f, 0.f, 0.f, 0.f};
        #pragma unroll
        for (int ks = 0; ks < 8; ks++) {
            #pragma unroll
            for (int n = 0; n < 8; n++) {
                bf16x8 b = *(const bf16x8*)&Lw[((ks * 8 + n) * 64 + lane) * 8];
                pacc[n] = MFMA16(ha[ks], b, pacc[n]);
            }
        }
        const int t_out = 511 - k;
        float* obase = out + (size_t)prow * 512 * 128 + (size_t)t_out * 128;
        bf16* pst_w = Pst + w * 2176;  // this wave's region
        #pragma unroll
        for (int n = 0; n < 8; n++) {
            #pragma unroll
            for (int r = 0; r < 4; r++) {
                float p = sigm(pacc[n][r] + lbias[n]);
                pst_w[(l4 * 4 + r) * 136 + n * 16 + l15] = (bf16)p;
                if (cg == 0) obase[(size_t)r * 512 * 128 + n * 16 + l15] = p;
            }
        }
        if (k == 511) break;  // last step: prediction only

        // gates = [pred | h] @ Wdec^T
        f32x4 acc[4];
        #pragma unroll
        for (int n = 0; n < 4; n++) acc[n] = (f32x4){0.f, 0.f, 0.f, 0.f};
        // h part first (independent of pred staging)
        #pragma unroll
        for (int ks = 0; ks < 8; ks++) {
            #pragma unroll
            for (int n = 0; n < 4; n++) {
                bf16x8 b = *(const bf16x8*)&Bg[(((ks + 4) * 4 + n) * 64 + lane) * 8];
                acc[n] = MFMA16(ha[ks], b, acc[n]);
            }
        }
        // pred part from LDS staging (same wave wrote its own 16 rows)
        const bf16* pst_r = Pst + w * 2176 + l15 * 136 + k0;
        #pragma unroll
        for (int ks = 0; ks < 4; ks++) {
            bf16x8 a = *(const bf16x8*)(pst_r + ks * 32);
            #pragma unroll
            for (int n = 0; n < 4; n++) {
                bf16x8 b = *(const bf16x8*)&Bg[((ks * 4 + n) * 64 + lane) * 8];
                acc[n] = MFMA16(a, b, acc[n]);
            }
        }
        // epilogue
        bf16* hw = hbuf + ((k + 1) & 1) * 65536;
        #pragma unroll
        for (int r = 0; r < 4; r++) {
            float gi = sigm(acc[0][r] + bias_g[0]);
            float gf = sigm(acc[1][r] + bias_g[1]);
            float gg = tanhfast(acc[2][r] + bias_g[2]);
            float go = sigm(acc[3][r] + bias_g[3]);
            c[r] = gf * c[r] + gi * gg;
            float h = go * tanhfast(c[r]);
            hw[(prow + r) * 256 + ucol] = (bf16)h;
        }
        // row-group barrier
        bar_target += 16;
        __syncthreads();
        if (tid == 0) {
            __threadfence();
            atomicAdd(ctr, 1u);
            while (__hip_atomic_load(ctr, __ATOMIC_RELAXED, __HIP_MEMORY_SCOPE_AGENT) < bar_target)
                __builtin_amdgcn_s_sleep(2);
            __threadfence();
        }
        __syncthreads();
    }
}

extern "C" void kernel_launch(void* const* d_in, const int* in_sizes, int n_in,
                              void* d_out, int out_size, void* d_ws, size_t ws_size,
                              hipStream_t stream) {
    const float* x    = (const float*)d_in[0];
    const float* eWih = (const float*)d_in[1];
    const float* eWhh = (const float*)d_in[2];
    const float* ebih = (const float*)d_in[3];
    const float* ebhh = (const float*)d_in[4];
    const float* dWih = (const float*)d_in[5];
    const float* dWhh = (const float*)d_in[6];
    const float* dbih = (const float*)d_in[7];
    const float* dbhh = (const float*)d_in[8];
    const float* linW = (const float*)d_in[9];
    const float* linb = (const float*)d_in[10];
    float* out = (float*)d_out;

    // workspace layout (~1.9 MB)
    bf16* encB = (bf16*)d_ws;            // 393216 bf16
    bf16* decB = encB + 393216;          // 393216 bf16
    bf16* linB = decB + 393216;          // 32768 bf16
    bf16* hbuf = linB + 32768;           // 2 x 256 x 256 bf16 ping-pong
    unsigned* bars = (unsigned*)(hbuf + 131072);  // 4 x 64 uints

    hipLaunchKernelGGL(pack_kernel, dim3(3200), dim3(256), 0, stream,
                       eWih, eWhh, dWih, dWhh, linW, encB, decB, linB);
    hipLaunchKernelGGL(zero_kernel, dim3(257), dim3(256), 0, stream, (unsigned*)hbuf);
    hipLaunchKernelGGL(lstm_main, dim3(64), dim3(256), 0, stream,
                       x, ebih, ebhh, dbih, dbhh, linb, encB, decB, linB, hbuf, bars, out);
}

// Round 2
// 7934.136 us; speedup vs baseline: 1.0967x; 1.0967x over previous
//
#include <hip/hip_runtime.h>

// B=256, T=512, I=128, H=256, 4H=1024
// 64 persistent blocks = 4 row-groups (64 batch rows) x 16 col-groups (16 hidden units).
// Cross-block h exchange + barrier counters use agent-scope relaxed atomics (sc0/sc1
// cache-bypass ops) -> no __threadfence (no buffer_wbl2/buffer_inv L2 flushes per step).

typedef __bf16 bf16;
typedef bf16 bf16x8 __attribute__((ext_vector_type(8)));
typedef float f32x4 __attribute__((ext_vector_type(4)));
typedef unsigned u32;
typedef u32 u32x4 __attribute__((ext_vector_type(4)));

#define MFMA16(a, b, c) __builtin_amdgcn_mfma_f32_16x16x32_bf16((a), (b), (c), 0, 0, 0)
#define AT_LOAD(p)     __hip_atomic_load((p), __ATOMIC_RELAXED, __HIP_MEMORY_SCOPE_AGENT)
#define AT_STORE(p, v) __hip_atomic_store((p), (v), __ATOMIC_RELAXED, __HIP_MEMORY_SCOPE_AGENT)

__device__ __forceinline__ float sigm(float x) { return 1.0f / (1.0f + __expf(-x)); }
__device__ __forceinline__ float tanhfast(float x) { return 1.0f - 2.0f / (__expf(2.0f * x) + 1.0f); }

__device__ __forceinline__ bf16x8 load_h_frag(const u32* p) {
    u32x4 v;
    v.x = AT_LOAD(p); v.y = AT_LOAD(p + 1); v.z = AT_LOAD(p + 2); v.w = AT_LOAD(p + 3);
    return __builtin_bit_cast(bf16x8, v);
}

// ---------------- weight packing (unchanged layout) ----------------
__global__ void pack_kernel(const float* __restrict__ eWih, const float* __restrict__ eWhh,
                            const float* __restrict__ dWih, const float* __restrict__ dWhh,
                            const float* __restrict__ linW,
                            bf16* __restrict__ encB, bf16* __restrict__ decB, bf16* __restrict__ linB) {
    int idx = blockIdx.x * 256 + threadIdx.x;  // 0 .. 819199
    if (idx < 786432) {
        int which = idx / 393216;          // 0 = enc, 1 = dec
        int id = idx % 393216;
        int cg = id / 24576;
        int rem = id % 24576;
        int ks = rem / 2048;
        int n = (rem / 512) & 3;
        int lane = (rem >> 3) & 63;
        int e = rem & 7;
        int k = ks * 32 + (lane >> 4) * 8 + e;
        int col = n * 256 + cg * 16 + (lane & 15);
        const float* Wih = which ? dWih : eWih;
        const float* Whh = which ? dWhh : eWhh;
        float v = (k < 128) ? Wih[col * 128 + k] : Whh[col * 256 + (k - 128)];
        (which ? decB : encB)[id] = (bf16)v;
    } else if (idx < 819200) {
        int i3 = idx - 786432;             // 0 .. 32767
        int ks = i3 >> 12;
        int n = (i3 >> 9) & 7;
        int lane = (i3 >> 3) & 63;
        int e = i3 & 7;
        int k = ks * 32 + (lane >> 4) * 8 + e;
        int col = n * 16 + (lane & 15);
        linB[i3] = (bf16)linW[col * 256 + k];
    }
}

__global__ void zero_kernel(unsigned* __restrict__ p) {
    int i = blockIdx.x * 256 + threadIdx.x;
    if (i < 65792) p[i] = 0u;  // h ping-pong (65536 words) + barrier counters (256 words)
}

// ---------------- main persistent kernel ----------------
__global__ __launch_bounds__(256, 1)
void lstm_main(const float* __restrict__ x,
               const float* __restrict__ eb_ih, const float* __restrict__ eb_hh,
               const float* __restrict__ db_ih, const float* __restrict__ db_hh,
               const float* __restrict__ lin_b,
               const bf16* __restrict__ encB, const bf16* __restrict__ decB,
               const bf16* __restrict__ linB,
               u32* __restrict__ hbuf32, unsigned* __restrict__ bars,
               float* __restrict__ out) {
    __shared__ bf16 Bg[24576];         // 48 KB gate-weight fragments (this cg)
    __shared__ bf16 Lw[32768];         // 64 KB lin_W fragments (decoder)
    __shared__ bf16 Pst[4 * 16 * 136]; // 17 KB pred staging, per-wave, pitch 136

    const int bid = blockIdx.x;
    const int rg = bid >> 4;           // row-group 0..3  (64 batch rows)
    const int cg = bid & 15;           // col-group 0..15 (16 hidden units)
    const int tid = threadIdx.x;
    const int w = tid >> 6;
    const int lane = tid & 63;
    const int l15 = lane & 15, l4 = lane >> 4;
    const int rbase = rg * 64 + w * 16;       // wave's 16 batch rows
    const int ucol = cg * 16 + l15;           // this lane's hidden unit
    const int arow = rbase + l15;             // A-fragment row this lane loads
    const int k0 = l4 * 8;                    // A-fragment k sub-offset
    const int prow = rbase + l4 * 4;          // epilogue row base

    // load encoder gate weights into LDS
    {
        const f32x4* src = (const f32x4*)(encB + cg * 24576);
        f32x4* dst = (f32x4*)Bg;
        #pragma unroll
        for (int i = 0; i < 12; i++) dst[tid + 256 * i] = src[tid + 256 * i];
    }
    float bias_g[4];
    #pragma unroll
    for (int g = 0; g < 4; g++) bias_g[g] = eb_ih[g * 256 + ucol] + eb_hh[g * 256 + ucol];
    __syncthreads();

    unsigned* ctr = bars + rg * 64;    // 256B-separated per row-group
    unsigned bar_target = 0;
    float c[4] = {0.f, 0.f, 0.f, 0.f};

    const float* xrow = x + (size_t)arow * 512 * 128 + k0;  // x[arow][t][k0+..]

    // preload x fragments for t=0
    f32x4 xr[8];
    #pragma unroll
    for (int i = 0; i < 4; i++) {
        xr[2 * i]     = *(const f32x4*)(xrow + i * 32);
        xr[2 * i + 1] = *(const f32x4*)(xrow + i * 32 + 4);
    }

    // =================== encoder: 512 steps ===================
    for (int t = 0; t < 512; t++) {
        const u32* hr32 = hbuf32 + (t & 1) * 32768;
        u32* hw32 = hbuf32 + ((t + 1) & 1) * 32768;

        // issue h loads early (L2-bypass coherent reads)
        bf16x8 ha[8];
        const u32* hb32 = hr32 + arow * 128 + l4 * 4;
        #pragma unroll
        for (int ks = 0; ks < 8; ks++) ha[ks] = load_h_frag(hb32 + ks * 16);

        f32x4 acc[4];
        #pragma unroll
        for (int n = 0; n < 4; n++) acc[n] = (f32x4){0.f, 0.f, 0.f, 0.f};

        // x part (K 0..127), from prefetched registers
        #pragma unroll
        for (int ks = 0; ks < 4; ks++) {
            f32x4 xa = xr[2 * ks], xb = xr[2 * ks + 1];
            bf16x8 a;
            a[0] = (bf16)xa[0]; a[1] = (bf16)xa[1]; a[2] = (bf16)xa[2]; a[3] = (bf16)xa[3];
            a[4] = (bf16)xb[0]; a[5] = (bf16)xb[1]; a[6] = (bf16)xb[2]; a[7] = (bf16)xb[3];
            #pragma unroll
            for (int n = 0; n < 4; n++) {
                bf16x8 b = *(const bf16x8*)&Bg[((ks * 4 + n) * 64 + lane) * 8];
                acc[n] = MFMA16(a, b, acc[n]);
            }
        }
        // h part (K 128..383)
        #pragma unroll
        for (int ks = 0; ks < 8; ks++) {
            #pragma unroll
            for (int n = 0; n < 4; n++) {
                bf16x8 b = *(const bf16x8*)&Bg[(((ks + 4) * 4 + n) * 64 + lane) * 8];
                acc[n] = MFMA16(ha[ks], b, acc[n]);
            }
        }
        // epilogue: lane owns rows prow+r, unit ucol
        #pragma unroll
        for (int r = 0; r < 4; r++) {
            float gi = sigm(acc[0][r] + bias_g[0]);
            float gf = sigm(acc[1][r] + bias_g[1]);
            float gg = tanhfast(acc[2][r] + bias_g[2]);
            float go = sigm(acc[3][r] + bias_g[3]);
            c[r] = gf * c[r] + gi * gg;
            float h = go * tanhfast(c[r]);
            unsigned hv = (unsigned)__builtin_bit_cast(unsigned short, (bf16)h);
            unsigned hp = __shfl_xor(hv, 1);
            if (!(lane & 1))
                AT_STORE(&hw32[(prow + r) * 128 + cg * 8 + (l15 >> 1)], hv | (hp << 16));
        }
        // prefetch x for next step (latency hides under barrier)
        int tn = t < 511 ? t + 1 : 511;
        #pragma unroll
        for (int i = 0; i < 4; i++) {
            xr[2 * i]     = *(const f32x4*)(xrow + (size_t)tn * 128 + i * 32);
            xr[2 * i + 1] = *(const f32x4*)(xrow + (size_t)tn * 128 + i * 32 + 4);
        }
        // row-group barrier: syncthreads (drains stores) -> arrive -> all-thread poll
        bar_target += 16;
        __syncthreads();
        if (tid == 0) __hip_atomic_fetch_add(ctr, 1u, __ATOMIC_RELAXED, __HIP_MEMORY_SCOPE_AGENT);
        while (AT_LOAD(ctr) < bar_target) __builtin_amdgcn_s_sleep(1);
    }

    // =================== switch to decoder weights ===================
    // All 64 waves of this rg passed the last barrier => done reading enc Bg.
    {
        const f32x4* src = (const f32x4*)(decB + cg * 24576);
        f32x4* dst = (f32x4*)Bg;
        #pragma unroll
        for (int i = 0; i < 12; i++) dst[tid + 256 * i] = src[tid + 256 * i];
        const f32x4* s2 = (const f32x4*)linB;
        f32x4* d2 = (f32x4*)Lw;
        #pragma unroll
        for (int i = 0; i < 16; i++) d2[tid + 256 * i] = s2[tid + 256 * i];
    }
    #pragma unroll
    for (int g = 0; g < 4; g++) bias_g[g] = db_ih[g * 256 + ucol] + db_hh[g * 256 + ucol];
    float lbias[8];
    #pragma unroll
    for (int n = 0; n < 8; n++) lbias[n] = lin_b[n * 16 + l15];
    __syncthreads();

    const int ncg = cg >> 1;   // out columns this block writes: n == ncg, half == (cg&1)
    const int hsel = cg & 1;

    // =================== decoder: pred(k) then gates(k) ===================
    for (int k = 0; k < 512; k++) {
        const u32* hr32 = hbuf32 + (k & 1) * 32768;

        bf16x8 ha[8];
        const u32* hb32 = hr32 + arow * 128 + l4 * 4;
        #pragma unroll
        for (int ks = 0; ks < 8; ks++) ha[ks] = load_h_frag(hb32 + ks * 16);

        // pred = sigmoid(h @ lin_W^T + lin_b)  [64 x 128], redundant per block
        f32x4 pacc[8];
        #pragma unroll
        for (int n = 0; n < 8; n++) pacc[n] = (f32x4){0.f, 0.f, 0.f, 0.f};
        #pragma unroll
        for (int ks = 0; ks < 8; ks++) {
            #pragma unroll
            for (int n = 0; n < 8; n++) {
                bf16x8 b = *(const bf16x8*)&Lw[((ks * 8 + n) * 64 + lane) * 8];
                pacc[n] = MFMA16(ha[ks], b, pacc[n]);
            }
        }
        const int t_out = 511 - k;
        float* obase = out + (size_t)prow * 512 * 128 + (size_t)t_out * 128;
        bf16* pst_w = Pst + w * 2176;
        #pragma unroll
        for (int n = 0; n < 8; n++) {
            #pragma unroll
            for (int r = 0; r < 4; r++) {
                float p = sigm(pacc[n][r] + lbias[n]);
                pst_w[(l4 * 4 + r) * 136 + n * 16 + l15] = (bf16)p;
                if (n == ncg && (l15 >> 3) == hsel)
                    obase[(size_t)r * 512 * 128 + n * 16 + l15] = p;
            }
        }
        if (k == 511) break;  // last step: prediction only

        // gates = [pred | h] @ Wdec^T
        f32x4 acc[4];
        #pragma unroll
        for (int n = 0; n < 4; n++) acc[n] = (f32x4){0.f, 0.f, 0.f, 0.f};
        #pragma unroll
        for (int ks = 0; ks < 8; ks++) {
            #pragma unroll
            for (int n = 0; n < 4; n++) {
                bf16x8 b = *(const bf16x8*)&Bg[(((ks + 4) * 4 + n) * 64 + lane) * 8];
                acc[n] = MFMA16(ha[ks], b, acc[n]);
            }
        }
        const bf16* pst_r = Pst + w * 2176 + l15 * 136 + k0;
        #pragma unroll
        for (int ks = 0; ks < 4; ks++) {
            bf16x8 a = *(const bf16x8*)(pst_r + ks * 32);
            #pragma unroll
            for (int n = 0; n < 4; n++) {
                bf16x8 b = *(const bf16x8*)&Bg[((ks * 4 + n) * 64 + lane) * 8];
                acc[n] = MFMA16(a, b, acc[n]);
            }
        }
        // epilogue
        u32* hw32 = hbuf32 + ((k + 1) & 1) * 32768;
        #pragma unroll
        for (int r = 0; r < 4; r++) {
            float gi = sigm(acc[0][r] + bias_g[0]);
            float gf = sigm(acc[1][r] + bias_g[1]);
            float gg = tanhfast(acc[2][r] + bias_g[2]);
            float go = sigm(acc[3][r] + bias_g[3]);
            c[r] = gf * c[r] + gi * gg;
            float h = go * tanhfast(c[r]);
            unsigned hv = (unsigned)__builtin_bit_cast(unsigned short, (bf16)h);
            unsigned hp = __shfl_xor(hv, 1);
            if (!(lane & 1))
                AT_STORE(&hw32[(prow + r) * 128 + cg * 8 + (l15 >> 1)], hv | (hp << 16));
        }
        // row-group barrier
        bar_target += 16;
        __syncthreads();
        if (tid == 0) __hip_atomic_fetch_add(ctr, 1u, __ATOMIC_RELAXED, __HIP_MEMORY_SCOPE_AGENT);
        while (AT_LOAD(ctr) < bar_target) __builtin_amdgcn_s_sleep(1);
    }
}

extern "C" void kernel_launch(void* const* d_in, const int* in_sizes, int n_in,
                              void* d_out, int out_size, void* d_ws, size_t ws_size,
                              hipStream_t stream) {
    const float* x    = (const float*)d_in[0];
    const float* eWih = (const float*)d_in[1];
    const float* eWhh = (const float*)d_in[2];
    const float* ebih = (const float*)d_in[3];
    const float* ebhh = (const float*)d_in[4];
    const float* dWih = (const float*)d_in[5];
    const float* dWhh = (const float*)d_in[6];
    const float* dbih = (const float*)d_in[7];
    const float* dbhh = (const float*)d_in[8];
    const float* linW = (const float*)d_in[9];
    const float* linb = (const float*)d_in[10];
    float* out = (float*)d_out;

    // workspace layout (~1.9 MB)
    bf16* encB = (bf16*)d_ws;            // 393216 bf16
    bf16* decB = encB + 393216;          // 393216 bf16
    bf16* linB = decB + 393216;          // 32768 bf16
    u32*  hbuf = (u32*)(linB + 32768);   // 2 x 256 x 128 u32 ping-pong (bf16 pairs)
    unsigned* bars = (unsigned*)(hbuf + 65536);  // 4 x 64 uints

    hipLaunchKernelGGL(pack_kernel, dim3(3200), dim3(256), 0, stream,
                       eWih, eWhh, dWih, dWhh, linW, encB, decB, linB);
    hipLaunchKernelGGL(zero_kernel, dim3(257), dim3(256), 0, stream, hbuf);
    hipLaunchKernelGGL(lstm_main, dim3(64), dim3(256), 0, stream,
                       x, ebih, ebhh, dbih, dbhh, linb, encB, decB, linB, hbuf, bars, out);
}

// Round 4
// 4865.509 us; speedup vs baseline: 1.7883x; 1.6307x over previous
//
#include <hip/hip_runtime.h>

// B=256, T=512, I=128, H=256, 4H=1024
// 64 worker blocks = 4 row-groups (64 batch rows) x 16 col-groups (16 hidden units).
// Round-2 protocol (device-scope sc0+sc1 everywhere, proven over graph replays) with:
//  (a) h ping-pong stored in MFMA A-fragment order -> 8 coalesced dwordx4 loads/lane
//  (b) flag-line barrier (posted stores + 16-lane wide poll), no atomics, no fences.

typedef __bf16 bf16;
typedef bf16 bf16x8 __attribute__((ext_vector_type(8)));
typedef float f32x4 __attribute__((ext_vector_type(4)));
typedef unsigned u32;
typedef u32 u32x4 __attribute__((ext_vector_type(4)));

#define MFMA16(a, b, c) __builtin_amdgcn_mfma_f32_16x16x32_bf16((a), (b), (c), 0, 0, 0)
#define AT_STORE_DEV(p, v) __hip_atomic_store((p), (v), __ATOMIC_RELAXED, __HIP_MEMORY_SCOPE_AGENT)

__device__ __forceinline__ float sigm(float x) { return 1.0f / (1.0f + __expf(-x)); }
__device__ __forceinline__ float tanhfast(float x) { return 1.0f - 2.0f / (__expf(2.0f * x) + 1.0f); }

// Device-coherent (L1+L2 bypass) ops. Loads issued without wait; caller waits + sched_barrier.
__device__ __forceinline__ u32x4 load_hx4(const u32* p) {
    u32x4 v;
    asm volatile("global_load_dwordx4 %0, %1, off sc0 sc1" : "=v"(v) : "v"(p));
    return v;
}
__device__ __forceinline__ void store_h(u32* p, u32 v) {
    asm volatile("global_store_dword %0, %1, off sc0 sc1" :: "v"(p), "v"(v) : "memory");
}
__device__ __forceinline__ u32 load_flag(const u32* p) {
    u32 v;
    asm volatile("global_load_dword %0, %1, off sc0 sc1\n\ts_waitcnt vmcnt(0)"
                 : "=v"(v) : "v"(p) : "memory");
    return v;
}

// ---------------- weight packing (fragment layout, unchanged) ----------------
__global__ void pack_kernel(const float* __restrict__ eWih, const float* __restrict__ eWhh,
                            const float* __restrict__ dWih, const float* __restrict__ dWhh,
                            const float* __restrict__ linW,
                            bf16* __restrict__ encB, bf16* __restrict__ decB, bf16* __restrict__ linB) {
    int idx = blockIdx.x * 256 + threadIdx.x;  // 0 .. 819199
    if (idx < 786432) {
        int which = idx / 393216;          // 0 = enc, 1 = dec
        int id = idx % 393216;
        int cg = id / 24576;
        int rem = id % 24576;
        int ks = rem / 2048;
        int n = (rem / 512) & 3;
        int lane = (rem >> 3) & 63;
        int e = rem & 7;
        int k = ks * 32 + (lane >> 4) * 8 + e;
        int col = n * 256 + cg * 16 + (lane & 15);
        const float* Wih = which ? dWih : eWih;
        const float* Whh = which ? dWhh : eWhh;
        float v = (k < 128) ? Wih[col * 128 + k] : Whh[col * 256 + (k - 128)];
        (which ? decB : encB)[id] = (bf16)v;
    } else if (idx < 819200) {
        int i3 = idx - 786432;             // 0 .. 32767
        int ks = i3 >> 12;
        int n = (i3 >> 9) & 7;
        int lane = (i3 >> 3) & 63;
        int e = i3 & 7;
        int k = ks * 32 + (lane >> 4) * 8 + e;
        int col = n * 16 + (lane & 15);
        linB[i3] = (bf16)linW[col * 256 + k];
    }
}

__global__ void zero_kernel(unsigned* __restrict__ p) {
    int i = blockIdx.x * 256 + threadIdx.x;
    // h ping-pong (65536 words) + flags (256 words); agent stores -> visible to sc1 readers
    if (i < 65792) AT_STORE_DEV(&p[i], 0u);
}

// ---------------- main persistent kernel ----------------
__global__ __launch_bounds__(256, 1)
void lstm_main(const float* __restrict__ x,
               const float* __restrict__ eb_ih, const float* __restrict__ eb_hh,
               const float* __restrict__ db_ih, const float* __restrict__ db_hh,
               const float* __restrict__ lin_b,
               const bf16* __restrict__ encB, const bf16* __restrict__ decB,
               const bf16* __restrict__ linB,
               u32* __restrict__ hbuf32, u32* __restrict__ flags,
               float* __restrict__ out) {
    __shared__ bf16 Bg[24576];         // 48 KB gate-weight fragments (this cg)
    __shared__ bf16 Lw[32768];         // 64 KB lin_W fragments (decoder)
    __shared__ bf16 Pst[4 * 16 * 136]; // 17 KB pred staging, per-wave, pitch 136

    const int bid = blockIdx.x;
    const int rg = bid >> 4;           // row-group 0..3  (64 batch rows)
    const int cg = bid & 15;           // col-group 0..15 (16 hidden units)
    const int tid = threadIdx.x;
    const int w = tid >> 6;
    const int lane = tid & 63;
    const int l15 = lane & 15, l4 = lane >> 4;
    const int rbase = rg * 64 + w * 16;       // wave's 16 batch rows
    const int ucol = cg * 16 + l15;           // this lane's hidden unit
    const int arow = rbase + l15;             // A-fragment row this lane loads
    const int k0 = l4 * 8;                    // A-fragment k sub-offset
    const int prow = rbase + l4 * 4;          // epilogue row base

    // h fragment layout: hbuf[phase][rt=16][ks=8][256 words]
    //   reader: word = rt*2048 + ks*256 + lane*4 + j   (dwordx4 per ks)
    //   content: h[rbase + (lane&15)][ks*32 + (lane>>4)*8 + 2j,2j+1] packed lo/hi
    const int rt = rg * 4 + w;                // this wave's row tile (reads & writes same tile)
    const int htile_w = (cg >> 1) * 256;      // writer's ks-tile (cols cg*16.. live in ks=cg>>1)
    const int hgrp = ((cg & 1) * 2 + (l15 >> 3)) * 16;
    const int widx = (l15 & 7) >> 1;

    // load encoder gate weights into LDS
    {
        const f32x4* src = (const f32x4*)(encB + cg * 24576);
        f32x4* dst = (f32x4*)Bg;
        #pragma unroll
        for (int i = 0; i < 12; i++) dst[tid + 256 * i] = src[tid + 256 * i];
    }
    float bias_g[4];
    #pragma unroll
    for (int g = 0; g < 4; g++) bias_g[g] = eb_ih[g * 256 + ucol] + eb_hh[g * 256 + ucol];
    __syncthreads();

    u32* myflag = flags + rg * 64 + cg;          // 256 B per rg
    const u32* pollp = flags + rg * 64 + l15;    // 16-lane wide poll (lanes 16+ duplicate)
    u32 stepno = 0;
    float c[4] = {0.f, 0.f, 0.f, 0.f};

    const float* xrow = x + (size_t)arow * 512 * 128 + k0;  // x[arow][t][k0+..]

    // preload x fragments for t=0
    f32x4 xr[8];
    #pragma unroll
    for (int i = 0; i < 4; i++) {
        xr[2 * i]     = *(const f32x4*)(xrow + i * 32);
        xr[2 * i + 1] = *(const f32x4*)(xrow + i * 32 + 4);
    }

    // =================== encoder: 512 steps ===================
    for (int t = 0; t < 512; t++) {
        const u32* hr32 = hbuf32 + (t & 1) * 32768;
        u32* hw32 = hbuf32 + ((t + 1) & 1) * 32768;

        // h A-fragments: 8 coalesced dwordx4, device-coherent
        u32x4 hv[8];
        const u32* hb = hr32 + rt * 2048 + lane * 4;
        #pragma unroll
        for (int ks = 0; ks < 8; ks++) hv[ks] = load_hx4(hb + ks * 256);

        f32x4 acc[4];
        #pragma unroll
        for (int n = 0; n < 4; n++) acc[n] = (f32x4){0.f, 0.f, 0.f, 0.f};

        // x part (K 0..127) from prefetched registers (overlaps h-load latency)
        #pragma unroll
        for (int ks = 0; ks < 4; ks++) {
            f32x4 xa = xr[2 * ks], xb = xr[2 * ks + 1];
            bf16x8 a;
            a[0] = (bf16)xa[0]; a[1] = (bf16)xa[1]; a[2] = (bf16)xa[2]; a[3] = (bf16)xa[3];
            a[4] = (bf16)xb[0]; a[5] = (bf16)xb[1]; a[6] = (bf16)xb[2]; a[7] = (bf16)xb[3];
            #pragma unroll
            for (int n = 0; n < 4; n++) {
                bf16x8 b = *(const bf16x8*)&Bg[((ks * 4 + n) * 64 + lane) * 8];
                acc[n] = MFMA16(a, b, acc[n]);
            }
        }
        // wait h loads, then h part (K 128..383)
        asm volatile("s_waitcnt vmcnt(0)" ::: "memory");
        __builtin_amdgcn_sched_barrier(0);
        #pragma unroll
        for (int ks = 0; ks < 8; ks++) {
            bf16x8 a = __builtin_bit_cast(bf16x8, hv[ks]);
            #pragma unroll
            for (int n = 0; n < 4; n++) {
                bf16x8 b = *(const bf16x8*)&Bg[(((ks + 4) * 4 + n) * 64 + lane) * 8];
                acc[n] = MFMA16(a, b, acc[n]);
            }
        }
        // epilogue: lane owns rows prow+r, unit ucol; store h in fragment layout
        #pragma unroll
        for (int r = 0; r < 4; r++) {
            float gi = sigm(acc[0][r] + bias_g[0]);
            float gf = sigm(acc[1][r] + bias_g[1]);
            float gg = tanhfast(acc[2][r] + bias_g[2]);
            float go = sigm(acc[3][r] + bias_g[3]);
            c[r] = gf * c[r] + gi * gg;
            float h = go * tanhfast(c[r]);
            unsigned hvv = (unsigned)__builtin_bit_cast(unsigned short, (bf16)h);
            unsigned hp = __shfl_xor(hvv, 1);
            if (!(lane & 1))
                store_h(&hw32[rt * 2048 + htile_w + (hgrp + l4 * 4 + r) * 4 + widx],
                        hvv | (hp << 16));
        }
        // barrier: drain stores -> post flag -> prefetch x -> wide poll
        stepno++;
        __syncthreads();                       // drains all waves' h stores (vmcnt 0)
        if (tid == 0) store_h(myflag, stepno);
        int tn = t < 511 ? t + 1 : 511;        // x prefetch completes during poll
        #pragma unroll
        for (int i = 0; i < 4; i++) {
            xr[2 * i]     = *(const f32x4*)(xrow + (size_t)tn * 128 + i * 32);
            xr[2 * i + 1] = *(const f32x4*)(xrow + (size_t)tn * 128 + i * 32 + 4);
        }
        while (!__all((int)(load_flag(pollp) >= stepno))) __builtin_amdgcn_s_sleep(1);
    }

    // =================== switch to decoder weights ===================
    // every wave passed the t=511 poll => all blocks finished encoder reads of Bg
    {
        const f32x4* src = (const f32x4*)(decB + cg * 24576);
        f32x4* dst = (f32x4*)Bg;
        #pragma unroll
        for (int i = 0; i < 12; i++) dst[tid + 256 * i] = src[tid + 256 * i];
        const f32x4* s2 = (const f32x4*)linB;
        f32x4* d2 = (f32x4*)Lw;
        #pragma unroll
        for (int i = 0; i < 16; i++) d2[tid + 256 * i] = s2[tid + 256 * i];
    }
    #pragma unroll
    for (int g = 0; g < 4; g++) bias_g[g] = db_ih[g * 256 + ucol] + db_hh[g * 256 + ucol];
    float lbias[8];
    #pragma unroll
    for (int n = 0; n < 8; n++) lbias[n] = lin_b[n * 16 + l15];
    __syncthreads();

    const int ncg = cg >> 1;   // out columns this block writes: n == ncg, half == (cg&1)
    const int hsel = cg & 1;

    // =================== decoder: pred(k) then gates(k) ===================
    for (int k = 0; k < 512; k++) {
        const u32* hr32 = hbuf32 + (k & 1) * 32768;

        u32x4 hv[8];
        const u32* hb = hr32 + rt * 2048 + lane * 4;
        #pragma unroll
        for (int ks = 0; ks < 8; ks++) hv[ks] = load_hx4(hb + ks * 256);
        asm volatile("s_waitcnt vmcnt(0)" ::: "memory");
        __builtin_amdgcn_sched_barrier(0);
        bf16x8 ha[8];
        #pragma unroll
        for (int ks = 0; ks < 8; ks++) ha[ks] = __builtin_bit_cast(bf16x8, hv[ks]);

        // pred = sigmoid(h @ lin_W^T + lin_b)  [64 x 128], redundant per block
        f32x4 pacc[8];
        #pragma unroll
        for (int n = 0; n < 8; n++) pacc[n] = (f32x4){0.f, 0.f, 0.f, 0.f};
        #pragma unroll
        for (int ks = 0; ks < 8; ks++) {
            #pragma unroll
            for (int n = 0; n < 8; n++) {
                bf16x8 b = *(const bf16x8*)&Lw[((ks * 8 + n) * 64 + lane) * 8];
                pacc[n] = MFMA16(ha[ks], b, pacc[n]);
            }
        }
        const int t_out = 511 - k;
        float* obase = out + (size_t)prow * 512 * 128 + (size_t)t_out * 128;
        bf16* pst_w = Pst + w * 2176;
        #pragma unroll
        for (int n = 0; n < 8; n++) {
            #pragma unroll
            for (int r = 0; r < 4; r++) {
                float p = sigm(pacc[n][r] + lbias[n]);
                pst_w[(l4 * 4 + r) * 136 + n * 16 + l15] = (bf16)p;
                if (n == ncg && (l15 >> 3) == hsel)
                    obase[(size_t)r * 512 * 128 + n * 16 + l15] = p;
            }
        }
        if (k == 511) break;  // last step: prediction only

        // gates = [pred | h] @ Wdec^T
        f32x4 acc[4];
        #pragma unroll
        for (int n = 0; n < 4; n++) acc[n] = (f32x4){0.f, 0.f, 0.f, 0.f};
        #pragma unroll
        for (int ks = 0; ks < 8; ks++) {
            #pragma unroll
            for (int n = 0; n < 4; n++) {
                bf16x8 b = *(const bf16x8*)&Bg[(((ks + 4) * 4 + n) * 64 + lane) * 8];
                acc[n] = MFMA16(ha[ks], b, acc[n]);
            }
        }
        const bf16* pst_r = Pst + w * 2176 + l15 * 136 + k0;
        #pragma unroll
        for (int ks = 0; ks < 4; ks++) {
            bf16x8 a = *(const bf16x8*)(pst_r + ks * 32);
            #pragma unroll
            for (int n = 0; n < 4; n++) {
                bf16x8 b = *(const bf16x8*)&Bg[((ks * 4 + n) * 64 + lane) * 8];
                acc[n] = MFMA16(a, b, acc[n]);
            }
        }
        // epilogue
        u32* hw32 = hbuf32 + ((k + 1) & 1) * 32768;
        #pragma unroll
        for (int r = 0; r < 4; r++) {
            float gi = sigm(acc[0][r] + bias_g[0]);
            float gf = sigm(acc[1][r] + bias_g[1]);
            float gg = tanhfast(acc[2][r] + bias_g[2]);
            float go = sigm(acc[3][r] + bias_g[3]);
            c[r] = gf * c[r] + gi * gg;
            float h = go * tanhfast(c[r]);
            unsigned hvv = (unsigned)__builtin_bit_cast(unsigned short, (bf16)h);
            unsigned hp = __shfl_xor(hvv, 1);
            if (!(lane & 1))
                store_h(&hw32[rt * 2048 + htile_w + (hgrp + l4 * 4 + r) * 4 + widx],
                        hvv | (hp << 16));
        }
        // barrier
        stepno++;
        __syncthreads();
        if (tid == 0) store_h(myflag, stepno);
        while (!__all((int)(load_flag(pollp) >= stepno))) __builtin_amdgcn_s_sleep(1);
    }
}

extern "C" void kernel_launch(void* const* d_in, const int* in_sizes, int n_in,
                              void* d_out, int out_size, void* d_ws, size_t ws_size,
                              hipStream_t stream) {
    const float* x    = (const float*)d_in[0];
    const float* eWih = (const float*)d_in[1];
    const float* eWhh = (const float*)d_in[2];
    const float* ebih = (const float*)d_in[3];
    const float* ebhh = (const float*)d_in[4];
    const float* dWih = (const float*)d_in[5];
    const float* dWhh = (const float*)d_in[6];
    const float* dbih = (const float*)d_in[7];
    const float* dbhh = (const float*)d_in[8];
    const float* linW = (const float*)d_in[9];
    const float* linb = (const float*)d_in[10];
    float* out = (float*)d_out;

    // workspace layout (~1.9 MB)
    bf16* encB = (bf16*)d_ws;            // 393216 bf16
    bf16* decB = encB + 393216;          // 393216 bf16
    bf16* linB = decB + 393216;          // 32768 bf16
    u32*  hbuf = (u32*)(linB + 32768);   // 2 x 16 tiles x 8 ks x 256 u32 (fragment layout)
    u32*  flags = hbuf + 65536;          // 4 rg x 64 words

    hipLaunchKernelGGL(pack_kernel, dim3(3200), dim3(256), 0, stream,
                       eWih, eWhh, dWih, dWhh, linW, encB, decB, linB);
    hipLaunchKernelGGL(zero_kernel, dim3(257), dim3(256), 0, stream, hbuf);
    hipLaunchKernelGGL(lstm_main, dim3(64), dim3(256), 0, stream,
                       x, ebih, ebhh, dbih, dbhh, linb, encB, decB, linB, hbuf, flags, out);
}